// Round 4
// baseline (625.978 us; speedup 1.0000x reference)
//
#include <hip/hip_runtime.h>

// DeepSNNController: 3-layer LIF SNN, T=100, B=4096, 9 -> 96 -> 96 -> 48.
//
// R12 "LDS-weights, chunk-major" design. R9-R11 post-mortems: the register
// allocator refuses to keep 81 weights/lane resident (spills to scratch to
// chase occupancy tiers; VGPR=72 both rounds, FETCH +7MB). Pivot to a design
// robust to a ~64-72 VGPR allocation:
//   * Weights live in LDS in a CHUNK-MAJOR layout W[chunk][owner_lane] so
//     every weight read is a lane-contiguous ds_read_b128 (conflict-free by
//     construction). Per-lane: 18 weight-b128/t (vs P7's 216).
//   * Spikes are BATCH-PACKED: dword (residue r, j) holds 4 batches' 0/1
//     bytes for k=4j+r. One b128 feeds 4 ks x 4 batches; cvt amortized over
//     2 neurons (1.5 VALU/MAC in L2).
//   * NB=8 batches/block, BLOCK=384 (96 quads), grid=512 = exactly 2
//     blocks/CU (LDS 56,832 B each), 12 waves/CU, one dispatch round.
//
// Work split (quad v = tid>>2, lane residue r = tid&3):
//   p = v % 48, h = v / 48 (batch plane: batches 4h..4h+3)
//   L2: quad owns neurons {p, p+48} x 4 batches of plane h (weights 48/lane
//       streamed from LDS, 12 chunks)
//   L3: quad owns neuron p x 4 batches of plane h (6 chunks)
//   L1: per-thread whole dot: n1 = tid%96, bbp = tid/96 -> batches {2bbp,2bbp+1}
//
// Exactness (absmax must stay 0): identical P7 arithmetic as R9-R11 (which
// all passed absmax=0):
//   dot(K): mod-4 k-split, lane r owns residue r, fmaf chain ascending j
//   (k=4j+r); combine (c0+c1)+(c2+c3) via 2 quad-perm DPP exchange-adds
//   (IEEE fadd bitwise-commutative -> all lanes identical bits). K=9 L1:
//   tail-first r0=(q8+q0)+q4, verbatim. Products exact (spikes in {0,1});
//   LIF pinned: mn = ((0.92*mp) + (dot + b)) - reset. LIFs replicated across
//   the quad (identical inputs -> identical bits); lane bb==r stores batch r.
//
// Mapping spot-checks (hand-verified):
//   W2L[7001]: c=9,u=22,i=1 -> W2[53][54]; read lane(p=5,r=2) cc=3 wb.y ->
//     chain j=13, k=4*13+2=54  OK.
//   spike(n=17,b=6): writer n1=17,bbp=3 -> byte 498; reader h=1,r=1,j=4
//     dword 124 byte 2 -> batch 6  OK.

constexpr int T_STEPS = 100;
constexpr int BATCH   = 4096;
constexpr int D_INP   = 9;
constexpr int H       = 96;
constexpr int H3      = 48;
constexpr int NB      = 8;             // batches per block
constexpr int BLOCK   = 384;           // 96 quads
constexpr int NBLK    = BATCH / NB;    // 512 blocks = 2/CU exactly

__device__ __forceinline__ float lif_step(float sum, float bias, float& m) {
    const float cur   = __fadd_rn(sum, bias);
    const float mp    = m;
    const float reset = (mp > 1.0f) ? 1.0f : 0.0f;
    const float mn    = __fsub_rn(__fadd_rn(__fmul_rn(0.92f, mp), cur), reset);
    m = mn;
    return mn;
}

#if defined(__has_builtin)
#if __has_builtin(__builtin_amdgcn_mov_dpp)
#define SNN_HAS_DPP 1
#endif
#endif

// Quad exchange-and-add. CTRL=0xB1: quad_perm [1,0,3,2] (xor 1);
// CTRL=0x4E: quad_perm [2,3,0,1] (xor 2).
template <int CTRL>
__device__ __forceinline__ float xadd(float c) {
#ifdef SNN_HAS_DPP
    const int o = __builtin_amdgcn_mov_dpp(__float_as_int(c), CTRL, 0xF, 0xF, false);
    return __fadd_rn(c, __int_as_float(o));
#else
    return __fadd_rn(c, __shfl_xor(c, (CTRL == 0xB1) ? 1 : 2, 64));
#endif
}

// lanes r=0..3 hold P7 residue partials c_r; returns (c0+c1)+(c2+c3) in ALL lanes.
__device__ __forceinline__ float quad_red(float c) {
    return xadd<0x4E>(xadd<0xB1>(c));
}

// One packed spike dword (4 batches' bytes for one k) x one weight per neuron:
// advances 8 L2 chains (2 neurons x 4 batches). cvt_f32_ubyte{0..3} expected.
#define L2DW(dw, wA1, wB1)                                                    \
    {                                                                         \
        const unsigned _u = (dw);                                             \
        const float _s0 = (float)( _u        & 255u);                         \
        const float _s1 = (float)((_u >> 8)  & 255u);                         \
        const float _s2 = (float)((_u >> 16) & 255u);                         \
        const float _s3 = (float)( _u >> 24);                                 \
        accA[0] = fmaf((wA1), _s0, accA[0]); accB[0] = fmaf((wB1), _s0, accB[0]); \
        accA[1] = fmaf((wA1), _s1, accA[1]); accB[1] = fmaf((wB1), _s1, accB[1]); \
        accA[2] = fmaf((wA1), _s2, accA[2]); accB[2] = fmaf((wB1), _s2, accB[2]); \
        accA[3] = fmaf((wA1), _s3, accA[3]); accB[3] = fmaf((wB1), _s3, accB[3]); \
    }

#define L3DW(dw, w31)                                                         \
    {                                                                         \
        const unsigned _u = (dw);                                             \
        const float _s0 = (float)( _u        & 255u);                         \
        const float _s1 = (float)((_u >> 8)  & 255u);                         \
        const float _s2 = (float)((_u >> 16) & 255u);                         \
        const float _s3 = (float)( _u >> 24);                                 \
        acc3[0] = fmaf((w31), _s0, acc3[0]);                                  \
        acc3[1] = fmaf((w31), _s1, acc3[1]);                                  \
        acc3[2] = fmaf((w31), _s2, acc3[2]);                                  \
        acc3[3] = fmaf((w31), _s3, acc3[3]);                                  \
    }

__global__ __launch_bounds__(BLOCK, 1)
void snn_lw(const float* __restrict__ x,
            const float* __restrict__ W1g, const float* __restrict__ b1g,
            const float* __restrict__ W2g, const float* __restrict__ b2g,
            const float* __restrict__ W3g, const float* __restrict__ b3g,
            float* __restrict__ out)
{
    // Chunk-major weights: cell (c, u) = 4 floats; addr = (c*192 + u)*16 B.
    // W2L cell (c,u,i): u=(p<<2)|r, n = (c<6 ? p : p+48), k = 16*(c%6)+4*i+r.
    __shared__ __align__(16) float    W2L[12 * 192 * 4];   // 36864 B
    __shared__ __align__(16) float    W3L[ 6 * 192 * 4];   // 18432 B
    // Batch-packed spikes: dword (h, r, j) = bytes of batches 4h+0..3 for
    // neuron n with n&3==r, n>>2==j (i.e. k = 4j + r).
    __shared__ __align__(16) unsigned s1p[2 * 4 * 24];     //   768 B
    __shared__ __align__(16) unsigned s2p[2 * 4 * 24];     //   768 B
    // total 56,832 B -> exactly 2 blocks/CU.

    const int tid = threadIdx.x;
    const int v   = tid >> 2;              // quad 0..95
    const int r   = tid & 3;               // residue lane
    const int h   = (v >= 48) ? 1 : 0;     // batch plane
    const int p   = v - 48 * h;            // neuron-pair / L3 neuron 0..47
    const int u   = (p << 2) | r;          // weight owner id 0..191

    const int n1  = tid % 96;              // L1 neuron
    const int bbp = tid / 96;              // L1 batch pair 0..3
    const int bg0 = blockIdx.x * NB;

    // ---- one-time LDS weight fill (scattered global reads; L2-cached) ----
    for (int L = tid; L < 12 * 192 * 4; L += BLOCK) {
        const int c  = L / 768;
        const int rm = L - c * 768;
        const int uu = rm >> 2;
        const int i  = rm & 3;
        const int pp = uu >> 2, rr = uu & 3;
        const int n  = (c < 6) ? pp : pp + 48;
        const int cc = (c < 6) ? c : c - 6;
        W2L[L] = W2g[n * H + 16 * cc + 4 * i + rr];
    }
    for (int L = tid; L < 6 * 192 * 4; L += BLOCK) {
        const int c  = L / 768;
        const int rm = L - c * 768;
        const int uu = rm >> 2;
        const int i  = rm & 3;
        const int pp = uu >> 2, rr = uu & 3;
        W3L[L] = W3g[pp * H + 16 * c + 4 * i + rr];
    }

    // ---- tiny per-thread register state ----
    float w1[D_INP];
    #pragma unroll
    for (int k = 0; k < D_INP; ++k) w1[k] = W1g[n1 * D_INP + k];
    const float bb1 = b1g[n1];
    const float b2A = b2g[p];
    const float b2B = b2g[p + 48];
    const float b3v = b3g[p];

    float m1[2]  = {0.f, 0.f};
    float m2A[4] = {}, m2B[4] = {}, m3[4] = {};

    __syncthreads();   // weights visible

    const float*    w2base = &W2L[u * 4];
    const float*    w3base = &W3L[u * 4];
    const unsigned* s1base = &s1p[h * 96 + r * 24];
    const unsigned* s2base = &s2p[h * 96 + r * 24];
    // L1 spike-write byte base: batches b = 2*bbp + bi -> plane bbp>>1,
    // byte lane 2*(bbp&1)+bi (consecutive for bi=0,1).
    unsigned char* s1wb = (unsigned char*)s1p
        + (((bbp >> 1) * 96 + (n1 & 3) * 24 + (n1 >> 2)) << 2) + 2 * (bbp & 1);
    // L2 spike-write byte base for (plane h, row p&3), byte lane r.
    unsigned char* s2wb = (unsigned char*)s2p + ((h * 96 + (p & 3) * 24) << 2) + r;

    float* out_spk = out;
    float* out_mem = out + (size_t)T_STEPS * BATCH * H3;

    for (int t = 0; t < T_STEPS; ++t) {
        // ---- layer 1: 9 -> 96, whole dot per thread, P7 order verbatim ----
        {
            const float* xt = x + ((size_t)t * BATCH + bg0 + 2 * bbp) * D_INP;
            #pragma unroll
            for (int bi = 0; bi < 2; ++bi) {
                float q[D_INP];
                #pragma unroll
                for (int k = 0; k < D_INP; ++k)
                    q[k] = __fmul_rn(w1[k], xt[bi * D_INP + k]);   // exact
                const float r0 = __fadd_rn(__fadd_rn(q[8], q[0]), q[4]);
                const float r1 = __fadd_rn(q[1], q[5]);
                const float r2 = __fadd_rn(q[2], q[6]);
                const float r3 = __fadd_rn(q[3], q[7]);
                const float s  = __fadd_rn(__fadd_rn(r0, r1), __fadd_rn(r2, r3));
                const float mn = lif_step(s, bb1, m1[bi]);
                s1wb[bi] = (mn > 1.0f) ? (unsigned char)1 : (unsigned char)0;
            }
        }
        __syncthreads();   // BAR1: s1p visible

        // ---- layer 2: 96 -> 96 ----
        {
            float accA[4] = {}, accB[4] = {};
            #pragma unroll
            for (int cc = 0; cc < 6; ++cc) {
                const float4 wa = *(const float4*)(w2base + cc * 768);
                const float4 wb = *(const float4*)(w2base + (cc + 6) * 768);
                const uint4  sp = *(const uint4*)(s1base + 4 * cc);
                L2DW(sp.x, wa.x, wb.x)     // j = 4cc+0
                L2DW(sp.y, wa.y, wb.y)     // j = 4cc+1
                L2DW(sp.z, wa.z, wb.z)     // j = 4cc+2
                L2DW(sp.w, wa.w, wb.w)     // j = 4cc+3
            }
            float selA = 0.f, selB = 0.f;
            #pragma unroll
            for (int bb = 0; bb < 4; ++bb) {
                const float sA  = quad_red(accA[bb]);   // (c0+c1)+(c2+c3)
                const float sB  = quad_red(accB[bb]);
                const float mnA = lif_step(sA, b2A, m2A[bb]);
                const float mnB = lif_step(sB, b2B, m2B[bb]);
                selA = (bb == r) ? mnA : selA;          // lane r keeps batch r
                selB = (bb == r) ? mnB : selB;
            }
            s2wb[(p >> 2) * 4]        = (selA > 1.0f) ? (unsigned char)1 : (unsigned char)0;
            s2wb[((p >> 2) + 12) * 4] = (selB > 1.0f) ? (unsigned char)1 : (unsigned char)0;
        }
        __syncthreads();   // BAR2: s2p visible

        // ---- layer 3: 96 -> 48 ----
        {
            float acc3[4] = {};
            #pragma unroll
            for (int cc = 0; cc < 6; ++cc) {
                const float4 w3v = *(const float4*)(w3base + cc * 768);
                const uint4  sp  = *(const uint4*)(s2base + 4 * cc);
                L3DW(sp.x, w3v.x)
                L3DW(sp.y, w3v.y)
                L3DW(sp.z, w3v.z)
                L3DW(sp.w, w3v.w)
            }
            float selS = 0.f, selM = 0.f;
            #pragma unroll
            for (int bb = 0; bb < 4; ++bb) {
                const float s3 = quad_red(acc3[bb]);
                const float mn = lif_step(s3, b3v, m3[bb]);
                selS = (bb == r) ? ((mn > 1.0f) ? 1.0f : 0.0f) : selS;
                selM = (bb == r) ? mn : selM;
            }
            const size_t ob = ((size_t)t * BATCH + bg0 + 4 * h + r) * H3 + p;
            out_spk[ob] = selS;
            out_mem[ob] = selM;
        }
        // Hazards: next-t L1 writes s1p -> all L2 reads of t done before BAR2(t).
        // Next-t L2 writes s2p after BAR1(t+1) -> all L3 reads of t done (they
        // precede BAR1(t+1) in program order).  2 barriers/t.
    }
}

extern "C" void kernel_launch(void* const* d_in, const int* in_sizes, int n_in,
                              void* d_out, int out_size, void* d_ws, size_t ws_size,
                              hipStream_t stream)
{
    const float* x  = (const float*)d_in[0];
    const float* W1 = (const float*)d_in[1];
    const float* b1 = (const float*)d_in[2];
    const float* W2 = (const float*)d_in[3];
    const float* b2 = (const float*)d_in[4];
    const float* W3 = (const float*)d_in[5];
    const float* b3 = (const float*)d_in[6];
    float* out = (float*)d_out;

    snn_lw<<<dim3(NBLK), dim3(BLOCK), 0, stream>>>(
        x, W1, b1, W2, b2, W3, b3, out);
}

// Round 5
// 540.187 us; speedup vs baseline: 1.1588x; 1.1588x over previous
//
#include <hip/hip_runtime.h>

// DeepSNNController: 3-layer LIF SNN, T=100, B=4096, 9 -> 96 -> 96 -> 48.
//
// R13 "wave-autonomous" design. R9-R12 post-mortem: three different designs
// all ~500us with VALUBusy 48-62% and wall ~2x VALU-issue time. Invariant
// cause: 2 __syncthreads x 100 t serializing all waves of a big block at
// phase boundaries, with ~1.5 waves/SIMD to cover the drains. Fix: ONE WAVE
// OWNS 4 BATCHES END-TO-END. Spike exchange is intra-wave (same-wave DS ops
// execute in program order; only cross-wave visibility needs barriers), so
// the 100-step loop has ZERO barriers. Blocks (4 waves) exist only to share
// one LDS weight copy. Weights use the chunk-major 16B-cell layout that R12
// MEASURED at zero bank conflicts. 4-batch packing maximizes cvt/weight-read
// amortization: ~1450 VALU/lane/t, ~60 LDS ops/lane/t.
//
// Exactness (absmax must stay 0): identical P7 arithmetic as R9-R12 (all
// passed absmax=0):
//   dot(K): mod-4 k-split, lane r owns residue r (k = 4j+r), fmaf chain
//   ascending j; combine (c0+c1)+(c2+c3) via 2 quad-perm DPP exchange-adds
//   (IEEE fadd bitwise-commutative -> all lanes identical bits). K=9 L1:
//   tail-first r0=(q8+q0)+q4, verbatim. Products exact (spikes in {0,1});
//   LIF pinned: mn = ((0.92*mp) + (dot + b)) - reset. After quad_red all 4
//   lanes hold identical sums; lane r performs the LIF for batch r only.
//
// Per-wave layout (64 lanes; q = l>>2 quad, r = l&3 residue):
//   L1: lane l: batch bL = l>>4, neurons n1 = (l&15)+16i, i=0..5
//       (weights broadcast-read from W1L[96][12]; 16 lanes share a row).
//   L2: quad q owns neurons n2 = 16s+q, s=0..5; lane r: residue r chains for
//       all 4 batches (acc[6][4]); LIF/spike-write for batch r.
//   L3: quad q owns n3 = 16s+q, s=0..2; same scheme; lane r stores batch r.
// Spikes: batch-packed dwords s*p[wave][r][j] (byte b = batch b, k = 4j+r).
// x(t+1) register-prefetched (9 floats; 16 lanes share -> L1$ broadcast).
//
// Mapping spot-checks (hand-verified):
//   W2L cell (c=s*6+jq, l): [jj] = W2[16s+q][16jq+4jj+r]; lane (q=3,r=2),
//     s=1,jq=4,jj=1: W2[19][70]; chain j=17 -> k=4*17+2=70  OK.
//   spike(n=17,b=2): writer L1 lane l15=1,i=1 (n1=17,bL=2): byte
//     ((17&3)*24+(17>>2))*4+2 = (24+4)*4+2 = 114; reader r=1,j=4 dword
//     [1][4] = dword 28, byte 2 -> addr 114  OK.

constexpr int T_STEPS = 100;
constexpr int BATCH   = 4096;
constexpr int D_INP   = 9;
constexpr int H       = 96;
constexpr int H3      = 48;
constexpr int WAVES   = 4;
constexpr int BPW     = 4;               // batches per wave
constexpr int NB      = WAVES * BPW;     // 16 batches per block
constexpr int BLOCK   = WAVES * 64;      // 256 threads
constexpr int NBLK    = BATCH / NB;      // 256 blocks = 1 per CU

__device__ __forceinline__ float lif_step(float sum, float bias, float& m) {
    const float cur   = __fadd_rn(sum, bias);
    const float mp    = m;
    const float reset = (mp > 1.0f) ? 1.0f : 0.0f;
    const float mn    = __fsub_rn(__fadd_rn(__fmul_rn(0.92f, mp), cur), reset);
    m = mn;
    return mn;
}

#if defined(__has_builtin)
#if __has_builtin(__builtin_amdgcn_mov_dpp)
#define SNN_HAS_DPP 1
#endif
#endif

// Quad exchange-and-add. CTRL=0xB1: quad_perm [1,0,3,2] (xor 1);
// CTRL=0x4E: quad_perm [2,3,0,1] (xor 2).
template <int CTRL>
__device__ __forceinline__ float xadd(float c) {
#ifdef SNN_HAS_DPP
    const int o = __builtin_amdgcn_mov_dpp(__float_as_int(c), CTRL, 0xF, 0xF, false);
    return __fadd_rn(c, __int_as_float(o));
#else
    return __fadd_rn(c, __shfl_xor(c, (CTRL == 0xB1) ? 1 : 2, 64));
#endif
}

// lanes r=0..3 hold P7 residue partials c_r; returns (c0+c1)+(c2+c3) in ALL lanes.
__device__ __forceinline__ float quad_red(float c) {
    return xadd<0x4E>(xadd<0xB1>(c));
}

#define UNPACK4(dw, row)                                                      \
    sf[row][0] = (float)( (dw)        & 255u);                                \
    sf[row][1] = (float)(((dw) >> 8)  & 255u);                                \
    sf[row][2] = (float)(((dw) >> 16) & 255u);                                \
    sf[row][3] = (float)( (dw) >> 24);

// 16 fmas: weight component jj pairs with spike row jj (j = 4*jq+jj ascending).
#define FMA16(accv, wv)                                                       \
    accv[0] = fmaf(wv.x, sf[0][0], accv[0]);                                  \
    accv[1] = fmaf(wv.x, sf[0][1], accv[1]);                                  \
    accv[2] = fmaf(wv.x, sf[0][2], accv[2]);                                  \
    accv[3] = fmaf(wv.x, sf[0][3], accv[3]);                                  \
    accv[0] = fmaf(wv.y, sf[1][0], accv[0]);                                  \
    accv[1] = fmaf(wv.y, sf[1][1], accv[1]);                                  \
    accv[2] = fmaf(wv.y, sf[1][2], accv[2]);                                  \
    accv[3] = fmaf(wv.y, sf[1][3], accv[3]);                                  \
    accv[0] = fmaf(wv.z, sf[2][0], accv[0]);                                  \
    accv[1] = fmaf(wv.z, sf[2][1], accv[1]);                                  \
    accv[2] = fmaf(wv.z, sf[2][2], accv[2]);                                  \
    accv[3] = fmaf(wv.z, sf[2][3], accv[3]);                                  \
    accv[0] = fmaf(wv.w, sf[3][0], accv[0]);                                  \
    accv[1] = fmaf(wv.w, sf[3][1], accv[1]);                                  \
    accv[2] = fmaf(wv.w, sf[3][2], accv[2]);                                  \
    accv[3] = fmaf(wv.w, sf[3][3], accv[3]);

__global__ __launch_bounds__(BLOCK, 1)
void snn_wav(const float* __restrict__ x,
             const float* __restrict__ W1g, const float* __restrict__ b1g,
             const float* __restrict__ W2g, const float* __restrict__ b2g,
             const float* __restrict__ W3g, const float* __restrict__ b3g,
             float* __restrict__ out)
{
    // Chunk-major weights: cell (c, l) = 16 B; R12 measured this grid at
    // ZERO bank conflicts (16-lane phases -> 2-way max, free).
    __shared__ __align__(16) float    W2L[36 * 64 * 4];  // 36864 B
    __shared__ __align__(16) float    W3L[18 * 64 * 4];  // 18432 B
    __shared__ __align__(16) float    W1L[96 * 12];      //  4608 B
    __shared__ __align__(16) unsigned s1p[WAVES][4][24]; //  1536 B
    __shared__ __align__(16) unsigned s2p[WAVES][4][24]; //  1536 B
    // total 62976 B

    const int tid = threadIdx.x;
    const int w   = tid >> 6;     // wave 0..3
    const int l   = tid & 63;     // lane
    const int q   = l >> 2;       // quad 0..15
    const int r   = l & 3;        // residue lane
    const int l15 = l & 15;
    const int bL  = l >> 4;       // L1 batch 0..3
    const int bg0 = blockIdx.x * NB + w * BPW;   // wave's batch base

    // ---- one-time weight staging (scattered; L2-cached) ----
    for (int idx = tid; idx < 36 * 64; idx += BLOCK) {
        const int c = idx >> 6, ll = idx & 63;
        const int s = c / 6, jq = c % 6, qq = ll >> 2, rr = ll & 3;
        #pragma unroll
        for (int jj = 0; jj < 4; ++jj)
            W2L[idx * 4 + jj] = W2g[(16 * s + qq) * H + 16 * jq + 4 * jj + rr];
    }
    for (int idx = tid; idx < 18 * 64; idx += BLOCK) {
        const int c = idx >> 6, ll = idx & 63;
        const int s = c / 6, jq = c % 6, qq = ll >> 2, rr = ll & 3;
        #pragma unroll
        for (int jj = 0; jj < 4; ++jj)
            W3L[idx * 4 + jj] = W3g[(16 * s + qq) * H + 16 * jq + 4 * jj + rr];
    }
    for (int idx = tid; idx < 96 * 12; idx += BLOCK) {
        const int n = idx / 12, k = idx % 12;
        W1L[idx] = (k < 9) ? W1g[n * D_INP + k] : 0.0f;
    }

    // ---- small persistent register state ----
    float bb1[6], bb2[6], bb3[3];
    #pragma unroll
    for (int i = 0; i < 6; ++i) bb1[i] = b1g[l15 + 16 * i];
    #pragma unroll
    for (int s = 0; s < 6; ++s) bb2[s] = b2g[16 * s + q];
    #pragma unroll
    for (int s = 0; s < 3; ++s) bb3[s] = b3g[16 * s + q];
    float m1[6] = {}, m2[6] = {}, m3[3] = {};

    float xr[D_INP];
    {
        const float* xp = x + ((size_t)0 * BATCH + bg0 + bL) * D_INP;
        #pragma unroll
        for (int k = 0; k < D_INP; ++k) xr[k] = xp[k];
    }

    __syncthreads();   // THE ONLY BLOCK BARRIER (weights visible)

    unsigned char* s1b = (unsigned char*)&s1p[w][0][0];
    unsigned char* s2b = (unsigned char*)&s2p[w][0][0];
    float* out_spk = out;
    float* out_mem = out + (size_t)T_STEPS * BATCH * H3;

    #pragma unroll 1
    for (int t = 0; t < T_STEPS; ++t) {
        // ---- layer 1: 9 -> 96. Lane: batch bL, 6 neurons. P7 order verbatim ----
        #pragma unroll
        for (int i = 0; i < 6; ++i) {
            const int n1 = l15 + 16 * i;
            const float4 wa = *(const float4*)&W1L[n1 * 12];
            const float4 wb = *(const float4*)&W1L[n1 * 12 + 4];
            const float  w8 = W1L[n1 * 12 + 8];
            const float q0 = __fmul_rn(wa.x, xr[0]);   // exact products
            const float q1 = __fmul_rn(wa.y, xr[1]);
            const float q2 = __fmul_rn(wa.z, xr[2]);
            const float q3 = __fmul_rn(wa.w, xr[3]);
            const float q4 = __fmul_rn(wb.x, xr[4]);
            const float q5 = __fmul_rn(wb.y, xr[5]);
            const float q6 = __fmul_rn(wb.z, xr[6]);
            const float q7 = __fmul_rn(wb.w, xr[7]);
            const float q8 = __fmul_rn(w8,   xr[8]);
            const float r0 = __fadd_rn(__fadd_rn(q8, q0), q4);   // tail-first
            const float r1 = __fadd_rn(q1, q5);
            const float r2 = __fadd_rn(q2, q6);
            const float r3 = __fadd_rn(q3, q7);
            const float s  = __fadd_rn(__fadd_rn(r0, r1), __fadd_rn(r2, r3));
            const float mn = lif_step(s, bb1[i], m1[i]);
            s1b[((n1 & 3) * 24 + (n1 >> 2)) * 4 + bL] =
                (mn > 1.0f) ? (unsigned char)1 : (unsigned char)0;
        }
        // register-prefetch x(t+1): consumed next t, latency hides under L2/L3.
        if (t + 1 < T_STEPS) {
            const float* xp = x + ((size_t)(t + 1) * BATCH + bg0 + bL) * D_INP;
            #pragma unroll
            for (int k = 0; k < D_INP; ++k) xr[k] = xp[k];
        }
        // Same-wave DS ordering: LDS pipe processes a wave's ops in order;
        // fence stops any compiler reordering and drains the write queue.
        asm volatile("s_waitcnt lgkmcnt(0)" ::: "memory");

        // ---- layer 2: 96 -> 96 (acc[s][b]: neuron 16s+q, batch b, residue r) ----
        {
            float acc[6][4] = {};
            #pragma unroll
            for (int jq = 0; jq < 6; ++jq) {
                const uint4 sp = *(const uint4*)&s1p[w][r][4 * jq];  // broadcast
                float sf[4][4];
                UNPACK4(sp.x, 0) UNPACK4(sp.y, 1) UNPACK4(sp.z, 2) UNPACK4(sp.w, 3)
                #pragma unroll
                for (int s = 0; s < 6; ++s) {
                    const float4 wv = *(const float4*)&W2L[((s * 6 + jq) * 64 + l) * 4];
                    FMA16(acc[s], wv)
                }
            }
            #pragma unroll
            for (int s = 0; s < 6; ++s) {
                const float g0 = quad_red(acc[s][0]);   // (c0+c1)+(c2+c3)
                const float g1 = quad_red(acc[s][1]);
                const float g2 = quad_red(acc[s][2]);
                const float g3 = quad_red(acc[s][3]);
                const float sv = (r == 0) ? g0 : ((r == 1) ? g1 : ((r == 2) ? g2 : g3));
                const float mn = lif_step(sv, bb2[s], m2[s]);   // batch r only
                const int n2 = 16 * s + q;
                s2b[((n2 & 3) * 24 + (n2 >> 2)) * 4 + r] =
                    (mn > 1.0f) ? (unsigned char)1 : (unsigned char)0;
            }
        }
        asm volatile("s_waitcnt lgkmcnt(0)" ::: "memory");

        // ---- layer 3: 96 -> 48 (a3[s][b]: neuron 16s+q, s=0..2) ----
        {
            float a3[3][4] = {};
            #pragma unroll
            for (int jq = 0; jq < 6; ++jq) {
                const uint4 sp = *(const uint4*)&s2p[w][r][4 * jq];
                float sf[4][4];
                UNPACK4(sp.x, 0) UNPACK4(sp.y, 1) UNPACK4(sp.z, 2) UNPACK4(sp.w, 3)
                #pragma unroll
                for (int s = 0; s < 3; ++s) {
                    const float4 wv = *(const float4*)&W3L[((s * 6 + jq) * 64 + l) * 4];
                    FMA16(a3[s], wv)
                }
            }
            #pragma unroll
            for (int s = 0; s < 3; ++s) {
                const float g0 = quad_red(a3[s][0]);
                const float g1 = quad_red(a3[s][1]);
                const float g2 = quad_red(a3[s][2]);
                const float g3 = quad_red(a3[s][3]);
                const float sv = (r == 0) ? g0 : ((r == 1) ? g1 : ((r == 2) ? g2 : g3));
                const float mn = lif_step(sv, bb3[s], m3[s]);   // batch r only
                const size_t ob = ((size_t)t * BATCH + bg0 + r) * H3 + 16 * s + q;
                out_spk[ob] = (mn > 1.0f) ? 1.0f : 0.0f;
                out_mem[ob] = mn;
            }
        }
        // No end-of-loop fence needed: next-t L1/L2 LDS writes are ordered
        // behind this t's reads by same-wave program order in the LDS pipe.
    }
}

extern "C" void kernel_launch(void* const* d_in, const int* in_sizes, int n_in,
                              void* d_out, int out_size, void* d_ws, size_t ws_size,
                              hipStream_t stream)
{
    const float* x  = (const float*)d_in[0];
    const float* W1 = (const float*)d_in[1];
    const float* b1 = (const float*)d_in[2];
    const float* W2 = (const float*)d_in[3];
    const float* b2 = (const float*)d_in[4];
    const float* W3 = (const float*)d_in[5];
    const float* b3 = (const float*)d_in[6];
    float* out = (float*)d_out;

    snn_wav<<<dim3(NBLK), dim3(BLOCK), 0, stream>>>(
        x, W1, b1, W2, b2, W3, b3, out);
}

// Round 6
// 443.359 us; speedup vs baseline: 1.4119x; 1.2184x over previous
//
#include <hip/hip_runtime.h>

// DeepSNNController: 3-layer LIF SNN, T=100, B=4096, 9 -> 96 -> 96 -> 48.
//
// R14 = R13 (wave-autonomous, zero barriers in t-loop) with the decomposition
// changed from 4 waves x 4 batches to 8 WAVES x 2 BATCHES per block.
// R13 post-mortem: 435us, occupancy = 1 wave/SIMD, nothing saturated -- wall
// was ds_read->fma dependency latency with no co-resident wave to hide it
// (LDS pipe 4.3k cyc/t busy, VALU ~3k, wall 10.4k). 2 waves/SIMD lets one
// wave's VALU cover the other's LDS latency. Weight LDS traffic doubles
// (each wave re-reads all weights for 2 batches) -> predicted new floor
// ~6k cyc/t = ~260us. Biases moved to LDS to keep VGPR <= 128 (2-wave tier;
// gate: VGPR_Count > 128 or FETCH >> 10MB means spill -> invalid).
//
// Exactness (absmax must stay 0): identical P7 arithmetic as R9-R13 (all
// passed absmax=0):
//   dot(K): mod-4 k-split, lane r owns residue r (k = 4j+r), fmaf chain
//   ascending j; combine (c0+c1)+(c2+c3) via 2 quad-perm DPP exchange-adds
//   (IEEE fadd bitwise-commutative -> all lanes identical bits). K=9 L1:
//   tail-first r0=(q8+q0)+q4, verbatim. Products exact (spikes in {0,1});
//   LIF pinned: mn = ((0.92*mp) + (dot + b)) - reset. After quad_red all 4
//   lanes hold identical sums; lane r tracks batch r&1, lanes r<2 store.
//
// Per-wave layout (64 lanes; q = l>>2 quad, r = l&3 residue):
//   L1: lane l: batch bL = l>>5, neurons n1 = (l&31)+32i, i=0..2
//       (weights broadcast from W1L[96][12]; 32 lanes share a row).
//   L2: quad q owns neurons n2 = 16s+q, s=0..5; lane r: residue-r chains for
//       both batches (acc[6][2]); LIF on batch r&1; lanes r<2 write spikes.
//   L3: quad q owns n3 = 16s+q, s=0..2; same scheme; lanes r<2 store out.
// Spikes: ushort-packed s*u[wave][r][j]: byte b of ushort j = spike of
// neuron n (n&3==r, n>>2==j) for batch b. Lane reads 8 j's per uint4.
// Weights: chunk-major 16B cells (R12/R13-measured conflict-free pattern).
// x(t+1) register-prefetched during t.
//
// Mapping spot-checks (hand-verified):
//   W2L cell (c=s*6+jq, l)[jj] = W2[16s+q][16jq+4jj+r]; chunk jc reads cells
//     2jc (j=8jc..8jc+3) then 2jc+1 (j=8jc+4..8jc+7): j ascending  OK.
//   spike(n=17,b=1): writer lane l&31=17,i=0,bL=1: byte (1*24+4)*2+1 = 57;
//     reader r=1, jc=0: uint4 byte offset 48+... dword1 byte1 -> 48+8+1=57  OK.

constexpr int T_STEPS = 100;
constexpr int BATCH   = 4096;
constexpr int D_INP   = 9;
constexpr int H       = 96;
constexpr int H3      = 48;
constexpr int WAVES   = 8;
constexpr int BPW     = 2;               // batches per wave
constexpr int NB      = WAVES * BPW;     // 16 batches per block
constexpr int BLOCK   = WAVES * 64;      // 512 threads
constexpr int NBLK    = BATCH / NB;      // 256 blocks = 1 per CU

__device__ __forceinline__ float lif_step(float sum, float bias, float& m) {
    const float cur   = __fadd_rn(sum, bias);
    const float mp    = m;
    const float reset = (mp > 1.0f) ? 1.0f : 0.0f;
    const float mn    = __fsub_rn(__fadd_rn(__fmul_rn(0.92f, mp), cur), reset);
    m = mn;
    return mn;
}

#if defined(__has_builtin)
#if __has_builtin(__builtin_amdgcn_mov_dpp)
#define SNN_HAS_DPP 1
#endif
#endif

// Quad exchange-and-add. CTRL=0xB1: quad_perm [1,0,3,2] (xor 1);
// CTRL=0x4E: quad_perm [2,3,0,1] (xor 2).
template <int CTRL>
__device__ __forceinline__ float xadd(float c) {
#ifdef SNN_HAS_DPP
    const int o = __builtin_amdgcn_mov_dpp(__float_as_int(c), CTRL, 0xF, 0xF, false);
    return __fadd_rn(c, __int_as_float(o));
#else
    return __fadd_rn(c, __shfl_xor(c, (CTRL == 0xB1) ? 1 : 2, 64));
#endif
}

// lanes r=0..3 hold P7 residue partials c_r; returns (c0+c1)+(c2+c3) in ALL lanes.
__device__ __forceinline__ float quad_red(float c) {
    return xadd<0x4E>(xadd<0xB1>(c));
}

// dword = ushorts {j0=2m, j0+1}: bytes [b0(j0), b1(j0), b0(j0+1), b1(j0+1)].
#define UNPACK2(dw, row)                                                      \
    sf[row][0]     = (float)( (dw)        & 255u);                            \
    sf[row][1]     = (float)(((dw) >> 8)  & 255u);                            \
    sf[(row)+1][0] = (float)(((dw) >> 16) & 255u);                            \
    sf[(row)+1][1] = (float)( (dw) >> 24);

// 8 fmas: weight component jj pairs with sf row jj (j ascending per chain).
#define FMA8(accv, wv, base)                                                  \
    accv[0] = fmaf(wv.x, sf[(base)+0][0], accv[0]);                           \
    accv[1] = fmaf(wv.x, sf[(base)+0][1], accv[1]);                           \
    accv[0] = fmaf(wv.y, sf[(base)+1][0], accv[0]);                           \
    accv[1] = fmaf(wv.y, sf[(base)+1][1], accv[1]);                           \
    accv[0] = fmaf(wv.z, sf[(base)+2][0], accv[0]);                           \
    accv[1] = fmaf(wv.z, sf[(base)+2][1], accv[1]);                           \
    accv[0] = fmaf(wv.w, sf[(base)+3][0], accv[0]);                           \
    accv[1] = fmaf(wv.w, sf[(base)+3][1], accv[1]);

__global__ __launch_bounds__(BLOCK, 2)
void snn_w8(const float* __restrict__ x,
            const float* __restrict__ W1g, const float* __restrict__ b1g,
            const float* __restrict__ W2g, const float* __restrict__ b2g,
            const float* __restrict__ W3g, const float* __restrict__ b3g,
            float* __restrict__ out)
{
    __shared__ __align__(16) float          W2L[36 * 64 * 4];    // 36864 B
    __shared__ __align__(16) float          W3L[18 * 64 * 4];    // 18432 B
    __shared__ __align__(16) float          W1L[96 * 12];        //  4608 B
    __shared__ __align__(16) float          b1L[96], b2L[96], b3L[48];
    __shared__ __align__(16) unsigned short s1u[WAVES][4][24];   //  1536 B
    __shared__ __align__(16) unsigned short s2u[WAVES][4][24];   //  1536 B
    // total 63,936 B -> 1 block/CU (grid 256), 8 waves/CU = 2/SIMD.

    const int tid = threadIdx.x;
    const int w   = tid >> 6;     // wave 0..7
    const int l   = tid & 63;     // lane
    const int q   = l >> 2;       // quad 0..15
    const int r   = l & 3;        // residue lane
    const int r01 = r & 1;        // this lane's batch (0/1)
    const int bL  = l >> 5;       // L1 batch 0..1
    const int bg0 = blockIdx.x * NB + w * BPW;   // wave's batch base

    // ---- one-time weight/bias staging (scattered; L2-cached) ----
    for (int idx = tid; idx < 36 * 64; idx += BLOCK) {
        const int c = idx >> 6, ll = idx & 63;
        const int s = c / 6, jq = c % 6, qq = ll >> 2, rr = ll & 3;
        #pragma unroll
        for (int jj = 0; jj < 4; ++jj)
            W2L[idx * 4 + jj] = W2g[(16 * s + qq) * H + 16 * jq + 4 * jj + rr];
    }
    for (int idx = tid; idx < 18 * 64; idx += BLOCK) {
        const int c = idx >> 6, ll = idx & 63;
        const int s = c / 6, jq = c % 6, qq = ll >> 2, rr = ll & 3;
        #pragma unroll
        for (int jj = 0; jj < 4; ++jj)
            W3L[idx * 4 + jj] = W3g[(16 * s + qq) * H + 16 * jq + 4 * jj + rr];
    }
    for (int idx = tid; idx < 96 * 12; idx += BLOCK) {
        const int n = idx / 12, k = idx % 12;
        W1L[idx] = (k < 9) ? W1g[n * D_INP + k] : 0.0f;
    }
    if (tid < 96) { b1L[tid] = b1g[tid]; b2L[tid] = b2g[tid]; }
    if (tid < 48) { b3L[tid] = b3g[tid]; }

    float m1[3] = {}, m2[6] = {}, m3[3] = {};

    // x pointer for this lane's L1 batch; advanced by one timestep per t.
    const float* xp = x + (size_t)(bg0 + bL) * D_INP;
    float xr[D_INP];
    #pragma unroll
    for (int k = 0; k < D_INP; ++k) xr[k] = xp[k];

    // output pointers for this lane's batch (valid for lanes r<2).
    float* ps = out + (size_t)(bg0 + r01) * H3 + q;
    float* pm = ps + (size_t)T_STEPS * BATCH * H3;

    __syncthreads();   // THE ONLY BLOCK BARRIER (weights/biases visible)

    unsigned char* s1b = (unsigned char*)&s1u[w][0][0];
    unsigned char* s2b = (unsigned char*)&s2u[w][0][0];

    #pragma unroll 1
    for (int t = 0; t < T_STEPS; ++t) {
        // ---- layer 1: 9 -> 96. Lane: batch bL, 3 neurons. P7 order verbatim ----
        #pragma unroll
        for (int i = 0; i < 3; ++i) {
            const int n1 = (l & 31) + 32 * i;
            const float4 wa = *(const float4*)&W1L[n1 * 12];
            const float4 wb = *(const float4*)&W1L[n1 * 12 + 4];
            const float  w8 = W1L[n1 * 12 + 8];
            const float q0 = __fmul_rn(wa.x, xr[0]);   // exact products
            const float q1 = __fmul_rn(wa.y, xr[1]);
            const float q2 = __fmul_rn(wa.z, xr[2]);
            const float q3 = __fmul_rn(wa.w, xr[3]);
            const float q4 = __fmul_rn(wb.x, xr[4]);
            const float q5 = __fmul_rn(wb.y, xr[5]);
            const float q6 = __fmul_rn(wb.z, xr[6]);
            const float q7 = __fmul_rn(wb.w, xr[7]);
            const float q8 = __fmul_rn(w8,   xr[8]);
            const float r0 = __fadd_rn(__fadd_rn(q8, q0), q4);   // tail-first
            const float r1 = __fadd_rn(q1, q5);
            const float r2 = __fadd_rn(q2, q6);
            const float r3 = __fadd_rn(q3, q7);
            const float s  = __fadd_rn(__fadd_rn(r0, r1), __fadd_rn(r2, r3));
            const float mn = lif_step(s, b1L[n1], m1[i]);
            s1b[((n1 & 3) * 24 + (n1 >> 2)) * 2 + bL] =
                (mn > 1.0f) ? (unsigned char)1 : (unsigned char)0;
        }
        // register-prefetch x(t+1): consumed next t, latency hides under L2/L3.
        if (t + 1 < T_STEPS) {
            xp += (size_t)BATCH * D_INP;
            #pragma unroll
            for (int k = 0; k < D_INP; ++k) xr[k] = xp[k];
        }
        // Same-wave DS ordering: drain writes; "memory" stops compiler reorder.
        asm volatile("s_waitcnt lgkmcnt(0)" ::: "memory");

        // ---- layer 2: 96 -> 96 (acc[s][b]: neuron 16s+q, batch b, residue r) ----
        {
            float acc[6][2] = {};
            #pragma unroll
            for (int jc = 0; jc < 3; ++jc) {
                const uint4 sp = *(const uint4*)&s1u[w][r][8 * jc];  // 8 j's
                float sf[8][2];
                UNPACK2(sp.x, 0) UNPACK2(sp.y, 2) UNPACK2(sp.z, 4) UNPACK2(sp.w, 6)
                #pragma unroll
                for (int s = 0; s < 6; ++s) {
                    const float4 w0 = *(const float4*)&W2L[((s * 6 + 2 * jc)     * 64 + l) * 4];
                    const float4 w1 = *(const float4*)&W2L[((s * 6 + 2 * jc + 1) * 64 + l) * 4];
                    FMA8(acc[s], w0, 0)
                    FMA8(acc[s], w1, 4)
                }
            }
            #pragma unroll
            for (int s = 0; s < 6; ++s) {
                const float g0 = quad_red(acc[s][0]);   // (c0+c1)+(c2+c3)
                const float g1 = quad_red(acc[s][1]);
                const float sv = r01 ? g1 : g0;
                const float mn = lif_step(sv, b2L[16 * s + q], m2[s]); // batch r01
                if (r < 2) {
                    const int n2 = 16 * s + q;
                    s2b[((n2 & 3) * 24 + (n2 >> 2)) * 2 + r] =
                        (mn > 1.0f) ? (unsigned char)1 : (unsigned char)0;
                }
            }
        }
        asm volatile("s_waitcnt lgkmcnt(0)" ::: "memory");

        // ---- layer 3: 96 -> 48 (a3[s][b]: neuron 16s+q, s=0..2) ----
        {
            float a3[3][2] = {};
            #pragma unroll
            for (int jc = 0; jc < 3; ++jc) {
                const uint4 sp = *(const uint4*)&s2u[w][r][8 * jc];
                float sf[8][2];
                UNPACK2(sp.x, 0) UNPACK2(sp.y, 2) UNPACK2(sp.z, 4) UNPACK2(sp.w, 6)
                #pragma unroll
                for (int s = 0; s < 3; ++s) {
                    const float4 w0 = *(const float4*)&W3L[((s * 6 + 2 * jc)     * 64 + l) * 4];
                    const float4 w1 = *(const float4*)&W3L[((s * 6 + 2 * jc + 1) * 64 + l) * 4];
                    FMA8(a3[s], w0, 0)
                    FMA8(a3[s], w1, 4)
                }
            }
            #pragma unroll
            for (int s = 0; s < 3; ++s) {
                const float g0 = quad_red(a3[s][0]);
                const float g1 = quad_red(a3[s][1]);
                const float sv = r01 ? g1 : g0;
                const float mn = lif_step(sv, b3L[16 * s + q], m3[s]); // batch r01
                if (r < 2) {
                    ps[16 * s] = (mn > 1.0f) ? 1.0f : 0.0f;
                    pm[16 * s] = mn;
                }
            }
            ps += (size_t)BATCH * H3;
            pm += (size_t)BATCH * H3;
        }
        // No end-of-loop fence: next-t L1/L2 LDS writes are ordered behind this
        // t's reads by same-wave program order + the per-layer fences above.
    }
}

extern "C" void kernel_launch(void* const* d_in, const int* in_sizes, int n_in,
                              void* d_out, int out_size, void* d_ws, size_t ws_size,
                              hipStream_t stream)
{
    const float* x  = (const float*)d_in[0];
    const float* W1 = (const float*)d_in[1];
    const float* b1 = (const float*)d_in[2];
    const float* W2 = (const float*)d_in[3];
    const float* b2 = (const float*)d_in[4];
    const float* W3 = (const float*)d_in[5];
    const float* b3 = (const float*)d_in[6];
    float* out = (float*)d_out;

    snn_w8<<<dim3(NBLK), dim3(BLOCK), 0, stream>>>(
        x, W1, b1, W2, b2, W3, b3, out);
}